// Round 4
// baseline (83.291 us; speedup 1.0000x reference)
//
#include <hip/hip_runtime.h>

// TaperingLayer: the reference's FFT pipeline collapses to
//   out = N^2 * M . crop . M^T   (complex 33x33 M, real 33x33 crop)
// where crop = img[x_pos:x_pos+33, y_pos:y_pos+33],
//   M[a][i] = (1-f_a) e(i0_a+1, i) + f_a e(i0_a+2, i),
//   e(r, i) = exp(-2*pi*I * r * (i-16) / 479),
//   i0_a = floor(239*a/16) (clipped to 477), f_a = c_a - i0_a (a=32 -> f=1),
// followed by ifftshift (index roll by +16 mod 33) on both output axes.
//
// Derivation: ifft2(fft2(K)*fft2(W)) = K (.) W (circular conv);
//   roll_s(a)(.)roll_t(b) = roll_{s+t}(a(.)b), fftshift = roll(+239),
//   239+239 = 478 = -1 (mod 479)  ->  output index (u+1)%479;
//   F(x~)(.)F(w~) = 479^2 * F(x~ * w~);  x*w is the crop at padded rows
//   223..255, and ifftshift (roll -239) puts crop index i at (i-16)%479.

#define PP 33
#define NROWS 256
#define NCOLS 256
#define NWIN 479
#define NSQ 229441.0f // 479*479

__global__ __launch_bounds__(256) void taper_kernel(
    const float* __restrict__ ref,
    const float* __restrict__ mov,
    const int* __restrict__ xp,
    const int* __restrict__ yp,
    float* __restrict__ out)
{
    __shared__ float  crop[PP][PP + 1];
    __shared__ float2 M[PP][PP];        // M[a][i] = g_a(i)
    __shared__ float2 C1[PP][PP + 1];   // C1[i][b] = sum_j crop[i][j] * M[b][j]

    const int bk   = blockIdx.x;
    const int feat = bk >> 6;   // 0 = ref, 1 = mov
    const int img  = bk & 63;
    const int t    = threadIdx.x;

    const int x0 = xp[0];
    const int y0 = yp[0];

    const float* src = (feat == 0 ? ref : mov) + (size_t)img * (NROWS * NCOLS);

    // ---- load the 33x33 crop ----
    for (int idx = t; idx < PP * PP; idx += 256) {
        int i = idx / PP, j = idx - i * PP;
        crop[i][j] = src[(x0 + i) * NCOLS + (y0 + j)];
    }

    // ---- build M (bilinear-regrid-fused DFT matrix) ----
    const float TPON = 6.28318530717958647692f / (float)NWIN; // 2*pi/479
    for (int idx = t; idx < PP * PP; idx += 256) {
        int a = idx / PP, i = idx - a * PP;
        int num = 239 * a;            // c_a = num/16 exactly
        int i0  = num >> 4;
        float f = (float)(num & 15) * 0.0625f;
        if (i0 >= NWIN - 1) { f += (float)(i0 - (NWIN - 2)); i0 = NWIN - 2; }
        int d  = i - 16;              // in [-16,16]
        int dm = d + NWIN;            // positive, == d (mod 479)
        int m1 = ((i0 + 1) * dm) % NWIN;   // exact integer phase reduction
        int m2 = ((i0 + 2) * dm) % NWIN;
        float s1, c1, s2, c2;
        sincosf(-TPON * (float)m1, &s1, &c1);
        sincosf(-TPON * (float)m2, &s2, &c2);
        float w1 = 1.0f - f;
        M[a][i] = make_float2(w1 * c1 + f * c2, w1 * s1 + f * s2);
    }
    __syncthreads();

    // ---- stage 1: contract columns: C1[i][b] = sum_j crop[i][j] * M[b][j] ----
    for (int idx = t; idx < PP * PP; idx += 256) {
        int i = idx / PP, b = idx - i * PP;
        float re = 0.f, im = 0.f;
        #pragma unroll
        for (int j = 0; j < PP; ++j) {
            float  cr = crop[i][j];
            float2 g  = M[b][j];
            re = fmaf(cr, g.x, re);
            im = fmaf(cr, g.y, im);
        }
        C1[i][b] = make_float2(re, im);
    }
    __syncthreads();

    // ---- stage 2: contract rows + ifftshift + scale + write ----
    float* obase = out + (size_t)feat * (64 * PP * PP * 2)
                       + (size_t)img  * (PP * PP * 2);
    for (int idx = t; idx < PP * PP; idx += 256) {
        int ao = idx / PP, bo = idx - ao * PP;   // output coords
        int a = ao + 16; if (a >= PP) a -= PP;   // ifftshift source coords
        int b = bo + 16; if (b >= PP) b -= PP;
        float re = 0.f, im = 0.f;
        #pragma unroll
        for (int i = 0; i < PP; ++i) {
            float2 g = M[a][i];
            float2 c = C1[i][b];
            re = fmaf(g.x, c.x, fmaf(-g.y, c.y, re));
            im = fmaf(g.x, c.y, fmaf( g.y, c.x, im));
        }
        obase[(ao * PP + bo) * 2 + 0] = re * NSQ;
        obase[(ao * PP + bo) * 2 + 1] = im * NSQ;
    }
}

extern "C" void kernel_launch(void* const* d_in, const int* in_sizes, int n_in,
                              void* d_out, int out_size, void* d_ws, size_t ws_size,
                              hipStream_t stream) {
    const float* ref = (const float*)d_in[0];
    const float* mov = (const float*)d_in[1];
    const int*   xp  = (const int*)d_in[2];
    const int*   yp  = (const int*)d_in[3];
    float* out = (float*)d_out;

    // one block per (feature, image): 2 * 64 = 128 blocks
    taper_kernel<<<128, 256, 0, stream>>>(ref, mov, xp, yp, out);
}

// Round 5
// 79.288 us; speedup vs baseline: 1.0505x; 1.0505x over previous
//
#include <hip/hip_runtime.h>

// TaperingLayer: the reference's FFT pipeline collapses to
//   out = N^2 * M . crop . M^T   (complex 33x33 M, real 33x33 crop)
// where crop = img[x_pos:x_pos+33, y_pos:y_pos+33],
//   M[a][i] = (1-f_a) e(i0_a+1, i) + f_a e(i0_a+2, i),
//   e(r, i) = exp(-2*pi*I * r * (i-16) / 479),
//   i0_a = floor(239*a/16) (clipped to 477), f_a = c_a - i0_a (a=32 -> f=1),
// followed by ifftshift (index roll by +16 mod 33) on both output axes.
//
// Derivation: ifft2(fft2(K)*fft2(W)) = K (.) W (circular conv);
//   roll_s(a)(.)roll_t(b) = roll_{s+t}(a(.)b), fftshift = roll(+239),
//   239+239 = 478 = -1 (mod 479)  ->  output index (u+1)%479;
//   F(x~)(.)F(w~) = 479^2 * F(x~ * w~);  x*w is the crop at padded rows
//   223..255, and ifftshift (roll -239) puts crop index i at (i-16)%479.
//
// R4: 256 -> 1024 threads/block. 1089 items / 256 = 4.25 serial items per
// thread dominated single-block latency; at 1024 threads it's ~1.06.
// A/B probe: if dur_us doesn't move, the 83us is harness/graph overhead
// (kernel absent from top-5 dispatches; fills at HBM ceiling dominate).

#define PP 33
#define NROWS 256
#define NCOLS 256
#define NWIN 479
#define NSQ 229441.0f // 479*479
#define NTHR 1024

__global__ __launch_bounds__(NTHR) void taper_kernel(
    const float* __restrict__ ref,
    const float* __restrict__ mov,
    const int* __restrict__ xp,
    const int* __restrict__ yp,
    float* __restrict__ out)
{
    __shared__ float  crop[PP][PP + 1];
    __shared__ float2 M[PP][PP];        // M[a][i] = g_a(i)
    __shared__ float2 C1[PP][PP + 1];   // C1[i][b] = sum_j crop[i][j] * M[b][j]

    const int bk   = blockIdx.x;
    const int feat = bk >> 6;   // 0 = ref, 1 = mov
    const int img  = bk & 63;
    const int t    = threadIdx.x;

    const int x0 = xp[0];
    const int y0 = yp[0];

    const float* src = (feat == 0 ? ref : mov) + (size_t)img * (NROWS * NCOLS);

    // ---- load the 33x33 crop (one element per thread) ----
    for (int idx = t; idx < PP * PP; idx += NTHR) {
        int i = idx / PP, j = idx - i * PP;
        crop[i][j] = src[(x0 + i) * NCOLS + (y0 + j)];
    }

    // ---- build M (bilinear-regrid-fused DFT matrix) ----
    const float TPON = 6.28318530717958647692f / (float)NWIN; // 2*pi/479
    for (int idx = t; idx < PP * PP; idx += NTHR) {
        int a = idx / PP, i = idx - a * PP;
        int num = 239 * a;            // c_a = num/16 exactly
        int i0  = num >> 4;
        float f = (float)(num & 15) * 0.0625f;
        if (i0 >= NWIN - 1) { f += (float)(i0 - (NWIN - 2)); i0 = NWIN - 2; }
        int d  = i - 16;              // in [-16,16]
        int dm = d + NWIN;            // positive, == d (mod 479)
        int m1 = ((i0 + 1) * dm) % NWIN;   // exact integer phase reduction
        int m2 = ((i0 + 2) * dm) % NWIN;
        float s1, c1, s2, c2;
        sincosf(-TPON * (float)m1, &s1, &c1);
        sincosf(-TPON * (float)m2, &s2, &c2);
        float w1 = 1.0f - f;
        M[a][i] = make_float2(w1 * c1 + f * c2, w1 * s1 + f * s2);
    }
    __syncthreads();

    // ---- stage 1: contract columns: C1[i][b] = sum_j crop[i][j] * M[b][j] ----
    for (int idx = t; idx < PP * PP; idx += NTHR) {
        int i = idx / PP, b = idx - i * PP;
        float re = 0.f, im = 0.f;
        #pragma unroll
        for (int j = 0; j < PP; ++j) {
            float  cr = crop[i][j];
            float2 g  = M[b][j];
            re = fmaf(cr, g.x, re);
            im = fmaf(cr, g.y, im);
        }
        C1[i][b] = make_float2(re, im);
    }
    __syncthreads();

    // ---- stage 2: contract rows + ifftshift + scale + write ----
    float* obase = out + (size_t)feat * (64 * PP * PP * 2)
                       + (size_t)img  * (PP * PP * 2);
    for (int idx = t; idx < PP * PP; idx += NTHR) {
        int ao = idx / PP, bo = idx - ao * PP;   // output coords
        int a = ao + 16; if (a >= PP) a -= PP;   // ifftshift source coords
        int b = bo + 16; if (b >= PP) b -= PP;
        float re = 0.f, im = 0.f;
        #pragma unroll
        for (int i = 0; i < PP; ++i) {
            float2 g = M[a][i];
            float2 c = C1[i][b];
            re = fmaf(g.x, c.x, fmaf(-g.y, c.y, re));
            im = fmaf(g.x, c.y, fmaf( g.y, c.x, im));
        }
        obase[(ao * PP + bo) * 2 + 0] = re * NSQ;
        obase[(ao * PP + bo) * 2 + 1] = im * NSQ;
    }
}

extern "C" void kernel_launch(void* const* d_in, const int* in_sizes, int n_in,
                              void* d_out, int out_size, void* d_ws, size_t ws_size,
                              hipStream_t stream) {
    const float* ref = (const float*)d_in[0];
    const float* mov = (const float*)d_in[1];
    const int*   xp  = (const int*)d_in[2];
    const int*   yp  = (const int*)d_in[3];
    float* out = (float*)d_out;

    // one block per (feature, image): 2 * 64 = 128 blocks
    taper_kernel<<<128, NTHR, 0, stream>>>(ref, mov, xp, yp, out);
}